// Round 5
// baseline (718.026 us; speedup 1.0000x reference)
//
#include <hip/hip_runtime.h>
#include <math.h>

#define BB 2
#define LL 2048
#define SS 2048
#define HH 8
#define EE 64
#define DD 64
#define HE (HH * EE)   // 512
// softmax scale = 1/sqrt(E) = 0.125

// ws layout (384 KB):
//   [0, 128K)     : m32  (B*H*L floats) -- BLAS-grid fp32 M_sp (bit-exact)
//   [128K, 256K)  : rank (B*H*L ints)
//   [256K, 384K)  : maxs (B*H*L floats)

typedef __attribute__((ext_vector_type(8))) short   bf16x8;   // MFMA A/B frag
typedef __attribute__((ext_vector_type(4))) float   f32x4;    // MFMA C/D frag
typedef __attribute__((ext_vector_type(8))) unsigned short u16x8;
typedef __attribute__((ext_vector_type(4))) unsigned short u16x4;

__device__ __forceinline__ unsigned short f2bf(float x) {   // fp32 -> bf16 RNE
    unsigned int u = __float_as_uint(x);
    return (unsigned short)((u + 0x7FFFu + ((u >> 16) & 1u)) >> 16);
}

// ---------- A: BLAS-grid fp32 M_sp, LDS dbuf broadcast, 2 q/lane, 8 waves -
// Arithmetic sequence IDENTICAL to the verified kernel, applied per query:
// score = sequential fmaf chain e=0..63 asc, single accumulator;
// r[j] chain over i8=0..15 sequential within each 128-key blk (bg = key/128);
// sub_ww = ((blk[4ww]+blk[4ww+1])+(blk[4ww+2]+blk[4ww+3]));
// s2048 = ((sub0+sub1)+(sub2+sub3)).  DO NOT REORDER.
//
// Round-4 lesson: 2 q/lane halves the broadcast ds_read count (LDS wall
// 327->164us) but 4-wave/256-grid left 1 wave/SIMD -> both pipes ~50% idle
// (serialized ds_read<->fmaf, no second wave to fill gaps). This version
// keeps 2 q/lane and restores 2 waves/SIMD: 512-thread / 8-wave blocks,
// wave w owns keys [256w, 256w+256) = blks {2w, 2w+1}. The blk->sub->s2048
// combine tree is reproduced exactly (blk indexed by key/128 as before).
// launch_bounds(512,2): 256-VGPR cap, body uses ~172 -> no spill (r2/r3
// lesson). Grid 256 = 1 block/CU, 8 waves/CU.
__global__ __launch_bounds__(512, 2)
void msp_blas(const float* __restrict__ Q, const float* __restrict__ K,
              float* __restrict__ m32, float* __restrict__ maxs) {
#pragma clang fp contract(off)
    __shared__ __align__(16) float ldsK[8][2][16 * 64];   // 64 KB, per-wave dbuf
    __shared__ float smx[2][8][64];                       // 4 KB
    __shared__ float sblk[2][16][64];                     // 8 KB

    const int bid = blockIdx.x;          // B*H*16 = 256
    const int lt = bid & 15, bh = bid >> 4;
    const int h = bh & 7, b = bh >> 3;
    const int t = threadIdx.x, lq = t & 63, w = t >> 6;   // w = 0..7
    const int l0 = lt * 128 + lq;        // first query of this lane
    const int l1 = l0 + 64;              // second query of this lane

    float qf0[64], qf1[64];
    {
        const float4* q0 = (const float4*)(Q + (((size_t)b * LL + l0) * HH + h) * EE);
        const float4* q1 = (const float4*)(Q + (((size_t)b * LL + l1) * HH + h) * EE);
#pragma unroll
        for (int i = 0; i < 16; i++) {
            float4 v = q0[i];
            qf0[4*i] = v.x; qf0[4*i+1] = v.y; qf0[4*i+2] = v.z; qf0[4*i+3] = v.w;
        }
#pragma unroll
        for (int i = 0; i < 16; i++) {
            float4 v = q1[i];
            qf1[4*i] = v.x; qf1[4*i+1] = v.y; qf1[4*i+2] = v.z; qf1[4*i+3] = v.w;
        }
    }

    const int wu = __builtin_amdgcn_readfirstlane(w);
    const float* Kb = K + (((size_t)b * SS) * HH + h) * EE;

    // staging map: lane covers key row (lq>>2) of the 16-key chunk,
    // 4x float4 at float col (lq&3)*4 + {0,16,32,48}. Wave base = 256 keys.
    const float* gstage = Kb + (size_t)(wu * 256 + (lq >> 2)) * HE + (lq & 3) * 4;
    const int lslot = (lq >> 2) * 64 + (lq & 3) * 4;

    float4 pf0, pf1, pf2, pf3;
    {   // prologue: chunk 0 -> buf 0
        const float* s = gstage;
        pf0 = *(const float4*)(s);
        pf1 = *(const float4*)(s + 16);
        pf2 = *(const float4*)(s + 32);
        pf3 = *(const float4*)(s + 48);
        float* dst = &ldsK[wu][0][lslot];
        *(float4*)(dst)      = pf0;
        *(float4*)(dst + 16) = pf1;
        *(float4*)(dst + 32) = pf2;
        *(float4*)(dst + 48) = pf3;
    }

    float mx0 = -1e30f, mx1 = -1e30f;
    float blk0[2], blk1[2];
#pragma unroll 1
    for (int lb = 0; lb < 2; ++lb) {     // local 128-key blk; global bg = 2w+lb
        float r0[8], r1[8];
#pragma unroll 1
        for (int ch = 0; ch < 8; ++ch) {
            const int g = lb * 8 + ch;                 // chunk 0..15
            const int gn = (g < 15) ? (g + 1) : 15;    // tail: reload (discarded)

            // issue next-chunk global loads (land after compute, before write)
            const float* s = gstage + (size_t)gn * (16 * HE);
            pf0 = *(const float4*)(s);
            pf1 = *(const float4*)(s + 16);
            pf2 = *(const float4*)(s + 32);
            pf3 = *(const float4*)(s + 48);

            const float* kb = &ldsK[wu][g & 1][0];
#pragma unroll 1
            for (int i2 = 0; i2 < 2; ++i2) {
                const int i8 = ch * 2 + i2;            // 0..15 within the blk
                float c[8], d[8];
#pragma unroll
                for (int j = 0; j < 8; j++) { c[j] = 0.f; d[j] = 0.f; }
#pragma unroll
                for (int e4 = 0; e4 < 16; ++e4) {
#pragma unroll
                    for (int j = 0; j < 8; j++) {
                        const float4 kv =
                            *(const float4*)&kb[(i2 * 8 + j) * 64 + e4 * 4];
                        c[j] = fmaf(qf0[4*e4+0], kv.x, c[j]);
                        c[j] = fmaf(qf0[4*e4+1], kv.y, c[j]);
                        c[j] = fmaf(qf0[4*e4+2], kv.z, c[j]);
                        c[j] = fmaf(qf0[4*e4+3], kv.w, c[j]);
                        d[j] = fmaf(qf1[4*e4+0], kv.x, d[j]);
                        d[j] = fmaf(qf1[4*e4+1], kv.y, d[j]);
                        d[j] = fmaf(qf1[4*e4+2], kv.z, d[j]);
                        d[j] = fmaf(qf1[4*e4+3], kv.w, d[j]);
                    }
                }
#pragma unroll
                for (int j = 0; j < 8; j++) {
                    mx0 = fmaxf(mx0, c[j]);
                    mx1 = fmaxf(mx1, d[j]);
                    if (i8 == 0) { r0[j] = c[j];               r1[j] = d[j]; }
                    else         { r0[j] = __fadd_rn(r0[j], c[j]);
                                   r1[j] = __fadd_rn(r1[j], d[j]); }
                }
            }

            // write prefetched chunk g+1 into the other wave-private buffer
            float* dst = &ldsK[wu][(g + 1) & 1][lslot];
            *(float4*)(dst)      = pf0;
            *(float4*)(dst + 16) = pf1;
            *(float4*)(dst + 32) = pf2;
            *(float4*)(dst + 48) = pf3;
        }
        blk0[lb] = __fadd_rn(
            __fadd_rn(__fadd_rn(r0[0], r0[1]), __fadd_rn(r0[2], r0[3])),
            __fadd_rn(__fadd_rn(r0[4], r0[5]), __fadd_rn(r0[6], r0[7])));
        blk1[lb] = __fadd_rn(
            __fadd_rn(__fadd_rn(r1[0], r1[1]), __fadd_rn(r1[2], r1[3])),
            __fadd_rn(__fadd_rn(r1[4], r1[5]), __fadd_rn(r1[6], r1[7])));
    }

    smx[0][w][lq] = mx0;
    smx[1][w][lq] = mx1;
    sblk[0][2 * w + 0][lq] = blk0[0];
    sblk[0][2 * w + 1][lq] = blk0[1];
    sblk[1][2 * w + 0][lq] = blk1[0];
    sblk[1][2 * w + 1][lq] = blk1[1];
    __syncthreads();
    if (w < 2) {     // wave 0 finalizes half 0, wave 1 half 1
        const int half = w;
        float m_all = smx[half][0][lq];
#pragma unroll
        for (int i = 1; i < 8; ++i) m_all = fmaxf(m_all, smx[half][i][lq]);
        // sub_ww = ((blk[4ww]+blk[4ww+1])+(blk[4ww+2]+blk[4ww+3])) -- old tree
        float subv[4];
#pragma unroll
        for (int ww = 0; ww < 4; ++ww)
            subv[ww] = __fadd_rn(
                __fadd_rn(sblk[half][4*ww+0][lq], sblk[half][4*ww+1][lq]),
                __fadd_rn(sblk[half][4*ww+2][lq], sblk[half][4*ww+3][lq]));
        const float s2048 = __fadd_rn(__fadd_rn(subv[0], subv[1]),
                                      __fadd_rn(subv[2], subv[3]));
        const float mean = __fmul_rn(s2048, 0.00048828125f);  // /2048 exact
        const int l = lt * 128 + half * 64 + lq;
        m32[((size_t)bh << 11) + l]  = __fsub_rn(m_all, mean);
        maxs[((size_t)bh << 11) + l] = m_all;
    }
}

// ---------- B: descending sort, ties -> lower index first -----------------
__global__ __launch_bounds__(256)
void sort_rank(const float* __restrict__ m32, int* __restrict__ rank) {
    __shared__ unsigned int k1[2048];
    __shared__ int pay[2048];
    const int bh = blockIdx.x;
    const int t = threadIdx.x;
    for (int i = t; i < 2048; i += 256) {
        unsigned int u = __float_as_uint(m32[((size_t)bh << 11) + i]);
        u = (u & 0x80000000u) ? ~u : (u | 0x80000000u);
        k1[i] = u; pay[i] = i;
    }
    __syncthreads();
    for (int k = 2; k <= 2048; k <<= 1) {
        for (int j = k >> 1; j > 0; j >>= 1) {
            for (int i = t; i < 2048; i += 256) {
                const int ixj = i ^ j;
                if (ixj > i) {
                    unsigned int a1 = k1[i], c1 = k1[ixj];
                    int pa = pay[i], pc = pay[ixj];
                    const bool pre = (a1 > c1) || (a1 == c1 && pa < pc);
                    const bool dir = ((i & k) == 0);
                    if (dir != pre) {
                        k1[i] = c1; k1[ixj] = a1;
                        pay[i] = pc; pay[ixj] = pa;
                    }
                }
            }
            __syncthreads();
        }
    }
    for (int i = t; i < 2048; i += 256)
        rank[((size_t)bh << 11) + pay[i]] = i;   // inverse permutation
}

// ---------- C: bf16 MFMA flash (two-pass softmax), scatter by rank --------
// Wave w owns 16 queries (rows lt*64 + w*16 .. +15) over the FULL S range.
// Per 64-s chunk: QK via mfma_16x16x32_bf16 (8), exp, P->LDS (A-layout),
// PV via mfma (8). K staged [s][e], V staged transposed [d][s], pitch 72
// bf16 (16B-aligned rows, bank-spread).
__global__ __launch_bounds__(256, 2)
void flash_mfma(const float* __restrict__ Q, const float* __restrict__ K,
                const float* __restrict__ V, const float* __restrict__ maxs,
                const int* __restrict__ rank, float* __restrict__ out) {
    __shared__ unsigned short ldsK[64 * 72];        // 9216 B
    __shared__ unsigned short ldsVT[64 * 72];       // 9216 B  (V transposed)
    __shared__ unsigned short ldsP[4 * 16 * 72];    // 9216 B  (per-wave P)

    const int bid = blockIdx.x;          // 512
    const int lt = bid & 31, bh = bid >> 5;
    const int h = bh & 7, b = bh >> 3;
    const int t = threadIdx.x, lane = t & 63, w = t >> 6;
    const int quad = lane >> 4, cl = lane & 15;

    const size_t kvbase = (((size_t)b * SS) * HH + h) * EE;

    // Q A-frags: A[m=cl][k=quad*8+j (+32*ef)]
    bf16x8 qa[2];
    {
        const float* qp = Q + (((size_t)b * LL + (lt * 64 + w * 16 + cl)) * HH + h) * EE
                          + quad * 8;
#pragma unroll
        for (int ef = 0; ef < 2; ++ef) {
            float4 a0 = *(const float4*)(qp + ef * 32);
            float4 a1 = *(const float4*)(qp + ef * 32 + 4);
            short* s = (short*)&qa[ef];
            s[0] = (short)f2bf(a0.x); s[1] = (short)f2bf(a0.y);
            s[2] = (short)f2bf(a0.z); s[3] = (short)f2bf(a0.w);
            s[4] = (short)f2bf(a1.x); s[5] = (short)f2bf(a1.y);
            s[6] = (short)f2bf(a1.z); s[7] = (short)f2bf(a1.w);
        }
    }

    // per-lane row constants (rows quad*4+reg)
    float negpm[4];
    int rk[4];
#pragma unroll
    for (int reg = 0; reg < 4; ++reg) {
        const int qg = lt * 64 + w * 16 + quad * 4 + reg;
        negpm[reg] = -0.125f * maxs[((size_t)bh << 11) + qg];
        rk[reg]    = rank[((size_t)bh << 11) + qg];
    }

    f32x4 accO[4];
#pragma unroll
    for (int nt = 0; nt < 4; ++nt) accO[nt] = (f32x4){0.f, 0.f, 0.f, 0.f};
    float ell[4] = {0.f, 0.f, 0.f, 0.f};

    const int pbase = w * (16 * 72);

#pragma unroll 1
    for (int c0 = 0; c0 < SS; c0 += 64) {
        __syncthreads();
        // ---- stage K[s][e] -> bf16, row-major pitch 72 ----
        {
            const int row = t >> 2, col0 = (t & 3) * 16;
            const float* gp = K + kvbase + (size_t)(c0 + row) * HE + col0;
            float4 f0 = ((const float4*)gp)[0];
            float4 f1 = ((const float4*)gp)[1];
            float4 f2 = ((const float4*)gp)[2];
            float4 f3 = ((const float4*)gp)[3];
            u16x8 w0 = { f2bf(f0.x), f2bf(f0.y), f2bf(f0.z), f2bf(f0.w),
                         f2bf(f1.x), f2bf(f1.y), f2bf(f1.z), f2bf(f1.w) };
            u16x8 w1 = { f2bf(f2.x), f2bf(f2.y), f2bf(f2.z), f2bf(f2.w),
                         f2bf(f3.x), f2bf(f3.y), f2bf(f3.z), f2bf(f3.w) };
            *(u16x8*)&ldsK[row * 72 + col0]     = w0;
            *(u16x8*)&ldsK[row * 72 + col0 + 8] = w1;
        }
        // ---- stage V transposed: VT[d][s] bf16, pitch 72 ----
        {
            const int s0 = (t & 15) * 4, d0 = (t >> 4) * 4;
            const float* gv = V + kvbase + (size_t)(c0 + s0) * HE + d0;
            float4 v0 = *(const float4*)(gv);
            float4 v1 = *(const float4*)(gv + HE);
            float4 v2 = *(const float4*)(gv + 2 * HE);
            float4 v3 = *(const float4*)(gv + 3 * HE);
            u16x4 p0 = { f2bf(v0.x), f2bf(v1.x), f2bf(v2.x), f2bf(v3.x) };
            u16x4 p1 = { f2bf(v0.y), f2bf(v1.y), f2bf(v2.y), f2bf(v3.y) };
            u16x4 p2 = { f2bf(v0.z), f2bf(v1.z), f2bf(v2.z), f2bf(v3.z) };
            u16x4 p3 = { f2bf(v0.w), f2bf(v1.w), f2bf(v2.w), f2bf(v3.w) };
            *(u16x4*)&ldsVT[(d0 + 0) * 72 + s0] = p0;
            *(u16x4*)&ldsVT[(d0 + 1) * 72 + s0] = p1;
            *(u16x4*)&ldsVT[(d0 + 2) * 72 + s0] = p2;
            *(u16x4*)&ldsVT[(d0 + 3) * 72 + s0] = p3;
        }
        __syncthreads();

        // ---- QK^T: S[m=q16][n=s64] = A(Q) x B(K), B[k=e][n=s]=K[s][e] ----
        f32x4 Sc[4];
#pragma unroll
        for (int nt = 0; nt < 4; ++nt) {
            bf16x8 bk0 = *(const bf16x8*)&ldsK[(nt * 16 + cl) * 72 + quad * 8];
            bf16x8 bk1 = *(const bf16x8*)&ldsK[(nt * 16 + cl) * 72 + quad * 8 + 32];
            f32x4 z = (f32x4){0.f, 0.f, 0.f, 0.f};
            z = __builtin_amdgcn_mfma_f32_16x16x32_bf16(qa[0], bk0, z, 0, 0, 0);
            z = __builtin_amdgcn_mfma_f32_16x16x32_bf16(qa[1], bk1, z, 0, 0, 0);
            Sc[nt] = z;
        }

        // ---- softmax numerator + P (bf16) into A-layout LDS ----
#pragma unroll
        for (int nt = 0; nt < 4; ++nt) {
#pragma unroll
            for (int reg = 0; reg < 4; ++reg) {
                const float p = __expf(fmaf(Sc[nt][reg], 0.125f, negpm[reg]));
                ell[reg] += p;
                ldsP[pbase + (quad * 4 + reg) * 72 + nt * 16 + cl] = f2bf(p);
            }
        }

        // ---- PV: O[m=q16][n=d64] += A(P) x B(V), B[k=s][n=d]=VT[d][s] ----
        bf16x8 pa0 = *(const bf16x8*)&ldsP[pbase + cl * 72 + quad * 8];
        bf16x8 pa1 = *(const bf16x8*)&ldsP[pbase + cl * 72 + quad * 8 + 32];
#pragma unroll
        for (int nt = 0; nt < 4; ++nt) {
            bf16x8 bv0 = *(const bf16x8*)&ldsVT[(nt * 16 + cl) * 72 + quad * 8];
            bf16x8 bv1 = *(const bf16x8*)&ldsVT[(nt * 16 + cl) * 72 + quad * 8 + 32];
            accO[nt] = __builtin_amdgcn_mfma_f32_16x16x32_bf16(pa0, bv0, accO[nt], 0, 0, 0);
            accO[nt] = __builtin_amdgcn_mfma_f32_16x16x32_bf16(pa1, bv1, accO[nt], 0, 0, 0);
        }
    }

    // ---- ell: reduce across the 16 lanes sharing each row (within quad) ----
#pragma unroll
    for (int reg = 0; reg < 4; ++reg) {
        float e = ell[reg];
        e += __shfl_xor(e, 1);
        e += __shfl_xor(e, 2);
        e += __shfl_xor(e, 4);
        e += __shfl_xor(e, 8);
        ell[reg] = 1.0f / e;
    }

    // ---- scatter O rows by rank ----
#pragma unroll
    for (int reg = 0; reg < 4; ++reg) {
        float* orow = out + (((size_t)b * LL + rk[reg]) * HH + h) * DD;
#pragma unroll
        for (int nt = 0; nt < 4; ++nt)
            orow[nt * 16 + cl] = accO[nt][reg] * ell[reg];
    }
}

extern "C" void kernel_launch(void* const* d_in, const int* in_sizes, int n_in,
                              void* d_out, int out_size, void* d_ws, size_t ws_size,
                              hipStream_t stream) {
    const float* Q = (const float*)d_in[0];
    const float* K = (const float*)d_in[1];
    const float* V = (const float*)d_in[2];
    float* out = (float*)d_out;

    float* m32  = (float*)d_ws;                          // 128 KB
    int*   rank = (int*)((char*)d_ws + 131072);          // 128 KB
    float* maxs = (float*)((char*)d_ws + 262144);        // 128 KB

    msp_blas<<<BB * HH * (LL / 128), 512, 0, stream>>>(Q, K, m32, maxs);
    sort_rank<<<BB * HH, 256, 0, stream>>>(m32, rank);
    flash_mfma<<<BB * HH * (LL / 64), 256, 0, stream>>>(Q, K, V, maxs, rank, out);
}

// Round 6
// 476.620 us; speedup vs baseline: 1.5065x; 1.5065x over previous
//
#include <hip/hip_runtime.h>
#include <math.h>

#define BB 2
#define LL 2048
#define SS 2048
#define HH 8
#define EE 64
#define DD 64
#define HE (HH * EE)   // 512
// softmax scale = 1/sqrt(E) = 0.125

// ws layout (384 KB):
//   [0, 128K)     : (unused -- m32 slot kept for layout stability)
//   [128K, 256K)  : rank (B*H*L ints)
//   [256K, 384K)  : maxs (B*H*L floats)
// d_out doubles as scratch for stage-A partials (512 KB of its 8 MB):
//   pmax[hf][bh][l] at out[ (hf*16+bh)*2048 + l ]
//   psum[hf][bh][l] at out[ 65536 + (hf*16+bh)*2048 + l ]
// flash_mfma fully overwrites out afterwards.

typedef __attribute__((ext_vector_type(8))) short   bf16x8;   // MFMA A/B frag
typedef __attribute__((ext_vector_type(4))) float   f32x4;    // MFMA C/D frag
typedef __attribute__((ext_vector_type(8))) unsigned short u16x8;
typedef __attribute__((ext_vector_type(4))) unsigned short u16x4;

__device__ __forceinline__ unsigned short f2bf(float x) {   // fp32 -> bf16 RNE
    unsigned int u = __float_as_uint(x);
    return (unsigned short)((u + 0x7FFFu + ((u >> 16) & 1u)) >> 16);
}

// ---------- A: BLAS-grid fp32 M_sp partials, LDS dbuf, 2 q/lane, key-split
// Arithmetic sequence IDENTICAL to the verified kernel, applied per query:
// score = sequential fmaf chain e=0..63 asc, single accumulator;
// r[j] chain over i8=0..15 sequential within each 128-key blk (bg = key/128);
// sub_ww = ((blk[4ww]+blk[4ww+1])+(blk[4ww+2]+blk[4ww+3]));
// s2048 = ((sub0+sub1)+(sub2+sub3)).  DO NOT REORDER.
//
// R5 lesson: 512-thread blocks get VGPR capped at 128 -> qf spills ->
// 669 MB scratch writes. ONLY the 256-thread/(256,1) shape is proven
// spill-free (R4: VGPR=172). R4 lesson: grid 256 = 1 wave/SIMD ->
// LDS pipe and VALU serialize (56% of the 164us LDS wall).
// This version: grid 512 = 2 blocks/CU = 2 waves/SIMD. Block (hf,lt,bh)
// covers 128 queries x 1024 keys; wave w owns keys hf*1024+[256w,256w+256)
// = global blks {8hf+2w, 8hf+2w+1}. Block emits pmax_hf (fmax, order-free)
// and psum_hf = fadd(sub_{2hf}, sub_{2hf+1}) -- an exact subtree of the
// verified combine. sort_rank finishes s2048 = fadd(psum0,psum1) and
// m_all = fmax(pmax0,pmax1): bit-exact.
__global__ __launch_bounds__(256, 1)
void msp_partial(const float* __restrict__ Q, const float* __restrict__ K,
                 float* __restrict__ pscratch) {
#pragma clang fp contract(off)
    __shared__ __align__(16) float ldsK[4][2][16 * 64];   // 32 KB, per-wave dbuf
    __shared__ float smx[2][4][64];                       // 2 KB
    __shared__ float sblk[2][8][64];                      // 4 KB

    const int bid = blockIdx.x;          // 512 = hf*256 + bh*16 + lt
    const int hf = bid >> 8;             // key half 0/1
    const int rem = bid & 255;
    const int lt = rem & 15, bh = rem >> 4;
    const int h = bh & 7, b = bh >> 3;
    const int t = threadIdx.x, lq = t & 63, w = t >> 6;   // w = 0..3
    const int l0 = lt * 128 + lq;        // first query of this lane
    const int l1 = l0 + 64;              // second query of this lane

    float qf0[64], qf1[64];
    {
        const float4* q0 = (const float4*)(Q + (((size_t)b * LL + l0) * HH + h) * EE);
        const float4* q1 = (const float4*)(Q + (((size_t)b * LL + l1) * HH + h) * EE);
#pragma unroll
        for (int i = 0; i < 16; i++) {
            float4 v = q0[i];
            qf0[4*i] = v.x; qf0[4*i+1] = v.y; qf0[4*i+2] = v.z; qf0[4*i+3] = v.w;
        }
#pragma unroll
        for (int i = 0; i < 16; i++) {
            float4 v = q1[i];
            qf1[4*i] = v.x; qf1[4*i+1] = v.y; qf1[4*i+2] = v.z; qf1[4*i+3] = v.w;
        }
    }

    const int wu = __builtin_amdgcn_readfirstlane(w);
    const float* Kb = K + (((size_t)b * SS) * HH + h) * EE;

    // staging map: lane covers key row (lq>>2) of the 16-key chunk,
    // 4x float4 at float col (lq&3)*4 + {0,16,32,48}.
    // Wave key base = hf*1024 + wu*256.
    const float* gstage =
        Kb + (size_t)(hf * 1024 + wu * 256 + (lq >> 2)) * HE + (lq & 3) * 4;
    const int lslot = (lq >> 2) * 64 + (lq & 3) * 4;

    float4 pf0, pf1, pf2, pf3;
    {   // prologue: chunk 0 -> buf 0
        const float* s = gstage;
        pf0 = *(const float4*)(s);
        pf1 = *(const float4*)(s + 16);
        pf2 = *(const float4*)(s + 32);
        pf3 = *(const float4*)(s + 48);
        float* dst = &ldsK[wu][0][lslot];
        *(float4*)(dst)      = pf0;
        *(float4*)(dst + 16) = pf1;
        *(float4*)(dst + 32) = pf2;
        *(float4*)(dst + 48) = pf3;
    }

    float mx0 = -1e30f, mx1 = -1e30f;
    float blk0[2], blk1[2];
#pragma unroll 1
    for (int lb = 0; lb < 2; ++lb) {     // local 128-key blk; global = 8hf+2w+lb
        float r0[8], r1[8];
#pragma unroll 1
        for (int ch = 0; ch < 8; ++ch) {
            const int g = lb * 8 + ch;                 // chunk 0..15
            const int gn = (g < 15) ? (g + 1) : 15;    // tail: reload (discarded)

            // issue next-chunk global loads (land after compute, before write)
            const float* s = gstage + (size_t)gn * (16 * HE);
            pf0 = *(const float4*)(s);
            pf1 = *(const float4*)(s + 16);
            pf2 = *(const float4*)(s + 32);
            pf3 = *(const float4*)(s + 48);

            const float* kb = &ldsK[wu][g & 1][0];
#pragma unroll 1
            for (int i2 = 0; i2 < 2; ++i2) {
                const int i8 = ch * 2 + i2;            // 0..15 within the blk
                float c[8], d[8];
#pragma unroll
                for (int j = 0; j < 8; j++) { c[j] = 0.f; d[j] = 0.f; }
#pragma unroll
                for (int e4 = 0; e4 < 16; ++e4) {
#pragma unroll
                    for (int j = 0; j < 8; j++) {
                        const float4 kv =
                            *(const float4*)&kb[(i2 * 8 + j) * 64 + e4 * 4];
                        c[j] = fmaf(qf0[4*e4+0], kv.x, c[j]);
                        c[j] = fmaf(qf0[4*e4+1], kv.y, c[j]);
                        c[j] = fmaf(qf0[4*e4+2], kv.z, c[j]);
                        c[j] = fmaf(qf0[4*e4+3], kv.w, c[j]);
                        d[j] = fmaf(qf1[4*e4+0], kv.x, d[j]);
                        d[j] = fmaf(qf1[4*e4+1], kv.y, d[j]);
                        d[j] = fmaf(qf1[4*e4+2], kv.z, d[j]);
                        d[j] = fmaf(qf1[4*e4+3], kv.w, d[j]);
                    }
                }
#pragma unroll
                for (int j = 0; j < 8; j++) {
                    mx0 = fmaxf(mx0, c[j]);
                    mx1 = fmaxf(mx1, d[j]);
                    if (i8 == 0) { r0[j] = c[j];               r1[j] = d[j]; }
                    else         { r0[j] = __fadd_rn(r0[j], c[j]);
                                   r1[j] = __fadd_rn(r1[j], d[j]); }
                }
            }

            // write prefetched chunk g+1 into the other wave-private buffer
            float* dst = &ldsK[wu][(g + 1) & 1][lslot];
            *(float4*)(dst)      = pf0;
            *(float4*)(dst + 16) = pf1;
            *(float4*)(dst + 32) = pf2;
            *(float4*)(dst + 48) = pf3;
        }
        blk0[lb] = __fadd_rn(
            __fadd_rn(__fadd_rn(r0[0], r0[1]), __fadd_rn(r0[2], r0[3])),
            __fadd_rn(__fadd_rn(r0[4], r0[5]), __fadd_rn(r0[6], r0[7])));
        blk1[lb] = __fadd_rn(
            __fadd_rn(__fadd_rn(r1[0], r1[1]), __fadd_rn(r1[2], r1[3])),
            __fadd_rn(__fadd_rn(r1[4], r1[5]), __fadd_rn(r1[6], r1[7])));
    }

    smx[0][w][lq] = mx0;
    smx[1][w][lq] = mx1;
    sblk[0][2 * w + 0][lq] = blk0[0];     // local blk order 0..7 = global 8hf..8hf+7
    sblk[0][2 * w + 1][lq] = blk0[1];
    sblk[1][2 * w + 0][lq] = blk1[0];
    sblk[1][2 * w + 1][lq] = blk1[1];
    __syncthreads();
    if (w < 2) {     // wave 0 finalizes query half 0, wave 1 half 1
        const int half = w;
        float m_all = fmaxf(fmaxf(smx[half][0][lq], smx[half][1][lq]),
                            fmaxf(smx[half][2][lq], smx[half][3][lq]));
        // sub_{2hf}   = tree over local blks 0..3  (= global 8hf..8hf+3)
        // sub_{2hf+1} = tree over local blks 4..7  (= global 8hf+4..8hf+7)
        const float sub_lo = __fadd_rn(
            __fadd_rn(sblk[half][0][lq], sblk[half][1][lq]),
            __fadd_rn(sblk[half][2][lq], sblk[half][3][lq]));
        const float sub_hi = __fadd_rn(
            __fadd_rn(sblk[half][4][lq], sblk[half][5][lq]),
            __fadd_rn(sblk[half][6][lq], sblk[half][7][lq]));
        const float psum = __fadd_rn(sub_lo, sub_hi);
        const int l = lt * 128 + half * 64 + lq;
        pscratch[(((size_t)hf * 16 + bh) << 11) + l]         = m_all;   // pmax
        pscratch[65536 + (((size_t)hf * 16 + bh) << 11) + l] = psum;    // psum
    }
}

// ---------- B: combine partials + descending sort, ties -> lower index ----
__global__ __launch_bounds__(256)
void sort_rank(const float* __restrict__ pscratch, float* __restrict__ maxs,
               int* __restrict__ rank) {
    __shared__ unsigned int k1[2048];
    __shared__ int pay[2048];
    const int bh = blockIdx.x;
    const int t = threadIdx.x;
    for (int i = t; i < 2048; i += 256) {
        // finish the exact verified combine tree:
        // m_all = fmax(pmax0, pmax1); s2048 = fadd(psum0, psum1)
        const float pmax0 = pscratch[(((size_t)bh) << 11) + i];
        const float pmax1 = pscratch[(((size_t)16 + bh) << 11) + i];
        const float psum0 = pscratch[65536 + (((size_t)bh) << 11) + i];
        const float psum1 = pscratch[65536 + (((size_t)16 + bh) << 11) + i];
        const float m_all = fmaxf(pmax0, pmax1);
        const float s2048 = __fadd_rn(psum0, psum1);
        const float mean  = __fmul_rn(s2048, 0.00048828125f);  // /2048 exact
        const float msp   = __fsub_rn(m_all, mean);
        maxs[(((size_t)bh) << 11) + i] = m_all;
        unsigned int u = __float_as_uint(msp);
        u = (u & 0x80000000u) ? ~u : (u | 0x80000000u);
        k1[i] = u; pay[i] = i;
    }
    __syncthreads();
    for (int k = 2; k <= 2048; k <<= 1) {
        for (int j = k >> 1; j > 0; j >>= 1) {
            for (int i = t; i < 2048; i += 256) {
                const int ixj = i ^ j;
                if (ixj > i) {
                    unsigned int a1 = k1[i], c1 = k1[ixj];
                    int pa = pay[i], pc = pay[ixj];
                    const bool pre = (a1 > c1) || (a1 == c1 && pa < pc);
                    const bool dir = ((i & k) == 0);
                    if (dir != pre) {
                        k1[i] = c1; k1[ixj] = a1;
                        pay[i] = pc; pay[ixj] = pa;
                    }
                }
            }
            __syncthreads();
        }
    }
    for (int i = t; i < 2048; i += 256)
        rank[(((size_t)bh) << 11) + pay[i]] = i;   // inverse permutation
}

// ---------- C: bf16 MFMA flash (two-pass softmax), scatter by rank --------
// Wave w owns 16 queries (rows lt*64 + w*16 .. +15) over the FULL S range.
// Per 64-s chunk: QK via mfma_16x16x32_bf16 (8), exp, P->LDS (A-layout),
// PV via mfma (8). K staged [s][e], V staged transposed [d][s], pitch 72
// bf16 (16B-aligned rows, bank-spread).
__global__ __launch_bounds__(256, 2)
void flash_mfma(const float* __restrict__ Q, const float* __restrict__ K,
                const float* __restrict__ V, const float* __restrict__ maxs,
                const int* __restrict__ rank, float* __restrict__ out) {
    __shared__ unsigned short ldsK[64 * 72];        // 9216 B
    __shared__ unsigned short ldsVT[64 * 72];       // 9216 B  (V transposed)
    __shared__ unsigned short ldsP[4 * 16 * 72];    // 9216 B  (per-wave P)

    const int bid = blockIdx.x;          // 512
    const int lt = bid & 31, bh = bid >> 5;
    const int h = bh & 7, b = bh >> 3;
    const int t = threadIdx.x, lane = t & 63, w = t >> 6;
    const int quad = lane >> 4, cl = lane & 15;

    const size_t kvbase = (((size_t)b * SS) * HH + h) * EE;

    // Q A-frags: A[m=cl][k=quad*8+j (+32*ef)]
    bf16x8 qa[2];
    {
        const float* qp = Q + (((size_t)b * LL + (lt * 64 + w * 16 + cl)) * HH + h) * EE
                          + quad * 8;
#pragma unroll
        for (int ef = 0; ef < 2; ++ef) {
            float4 a0 = *(const float4*)(qp + ef * 32);
            float4 a1 = *(const float4*)(qp + ef * 32 + 4);
            short* s = (short*)&qa[ef];
            s[0] = (short)f2bf(a0.x); s[1] = (short)f2bf(a0.y);
            s[2] = (short)f2bf(a0.z); s[3] = (short)f2bf(a0.w);
            s[4] = (short)f2bf(a1.x); s[5] = (short)f2bf(a1.y);
            s[6] = (short)f2bf(a1.z); s[7] = (short)f2bf(a1.w);
        }
    }

    // per-lane row constants (rows quad*4+reg)
    float negpm[4];
    int rk[4];
#pragma unroll
    for (int reg = 0; reg < 4; ++reg) {
        const int qg = lt * 64 + w * 16 + quad * 4 + reg;
        negpm[reg] = -0.125f * maxs[((size_t)bh << 11) + qg];
        rk[reg]    = rank[((size_t)bh << 11) + qg];
    }

    f32x4 accO[4];
#pragma unroll
    for (int nt = 0; nt < 4; ++nt) accO[nt] = (f32x4){0.f, 0.f, 0.f, 0.f};
    float ell[4] = {0.f, 0.f, 0.f, 0.f};

    const int pbase = w * (16 * 72);

#pragma unroll 1
    for (int c0 = 0; c0 < SS; c0 += 64) {
        __syncthreads();
        // ---- stage K[s][e] -> bf16, row-major pitch 72 ----
        {
            const int row = t >> 2, col0 = (t & 3) * 16;
            const float* gp = K + kvbase + (size_t)(c0 + row) * HE + col0;
            float4 f0 = ((const float4*)gp)[0];
            float4 f1 = ((const float4*)gp)[1];
            float4 f2 = ((const float4*)gp)[2];
            float4 f3 = ((const float4*)gp)[3];
            u16x8 w0 = { f2bf(f0.x), f2bf(f0.y), f2bf(f0.z), f2bf(f0.w),
                         f2bf(f1.x), f2bf(f1.y), f2bf(f1.z), f2bf(f1.w) };
            u16x8 w1 = { f2bf(f2.x), f2bf(f2.y), f2bf(f2.z), f2bf(f2.w),
                         f2bf(f3.x), f2bf(f3.y), f2bf(f3.z), f2bf(f3.w) };
            *(u16x8*)&ldsK[row * 72 + col0]     = w0;
            *(u16x8*)&ldsK[row * 72 + col0 + 8] = w1;
        }
        // ---- stage V transposed: VT[d][s] bf16, pitch 72 ----
        {
            const int s0 = (t & 15) * 4, d0 = (t >> 4) * 4;
            const float* gv = V + kvbase + (size_t)(c0 + s0) * HE + d0;
            float4 v0 = *(const float4*)(gv);
            float4 v1 = *(const float4*)(gv + HE);
            float4 v2 = *(const float4*)(gv + 2 * HE);
            float4 v3 = *(const float4*)(gv + 3 * HE);
            u16x4 p0 = { f2bf(v0.x), f2bf(v1.x), f2bf(v2.x), f2bf(v3.x) };
            u16x4 p1 = { f2bf(v0.y), f2bf(v1.y), f2bf(v2.y), f2bf(v3.y) };
            u16x4 p2 = { f2bf(v0.z), f2bf(v1.z), f2bf(v2.z), f2bf(v3.z) };
            u16x4 p3 = { f2bf(v0.w), f2bf(v1.w), f2bf(v2.w), f2bf(v3.w) };
            *(u16x4*)&ldsVT[(d0 + 0) * 72 + s0] = p0;
            *(u16x4*)&ldsVT[(d0 + 1) * 72 + s0] = p1;
            *(u16x4*)&ldsVT[(d0 + 2) * 72 + s0] = p2;
            *(u16x4*)&ldsVT[(d0 + 3) * 72 + s0] = p3;
        }
        __syncthreads();

        // ---- QK^T: S[m=q16][n=s64] = A(Q) x B(K), B[k=e][n=s]=K[s][e] ----
        f32x4 Sc[4];
#pragma unroll
        for (int nt = 0; nt < 4; ++nt) {
            bf16x8 bk0 = *(const bf16x8*)&ldsK[(nt * 16 + cl) * 72 + quad * 8];
            bf16x8 bk1 = *(const bf16x8*)&ldsK[(nt * 16 + cl) * 72 + quad * 8 + 32];
            f32x4 z = (f32x4){0.f, 0.f, 0.f, 0.f};
            z = __builtin_amdgcn_mfma_f32_16x16x32_bf16(qa[0], bk0, z, 0, 0, 0);
            z = __builtin_amdgcn_mfma_f32_16x16x32_bf16(qa[1], bk1, z, 0, 0, 0);
            Sc[nt] = z;
        }

        // ---- softmax numerator + P (bf16) into A-layout LDS ----
#pragma unroll
        for (int nt = 0; nt < 4; ++nt) {
#pragma unroll
            for (int reg = 0; reg < 4; ++reg) {
                const float p = __expf(fmaf(Sc[nt][reg], 0.125f, negpm[reg]));
                ell[reg] += p;
                ldsP[pbase + (quad * 4 + reg) * 72 + nt * 16 + cl] = f2bf(p);
            }
        }

        // ---- PV: O[m=q16][n=d64] += A(P) x B(V), B[k=s][n=d]=VT[d][s] ----
        bf16x8 pa0 = *(const bf16x8*)&ldsP[pbase + cl * 72 + quad * 8];
        bf16x8 pa1 = *(const bf16x8*)&ldsP[pbase + cl * 72 + quad * 8 + 32];
#pragma unroll
        for (int nt = 0; nt < 4; ++nt) {
            bf16x8 bv0 = *(const bf16x8*)&ldsVT[(nt * 16 + cl) * 72 + quad * 8];
            bf16x8 bv1 = *(const bf16x8*)&ldsVT[(nt * 16 + cl) * 72 + quad * 8 + 32];
            accO[nt] = __builtin_amdgcn_mfma_f32_16x16x32_bf16(pa0, bv0, accO[nt], 0, 0, 0);
            accO[nt] = __builtin_amdgcn_mfma_f32_16x16x32_bf16(pa1, bv1, accO[nt], 0, 0, 0);
        }
    }

    // ---- ell: reduce across the 16 lanes sharing each row (within quad) ----
#pragma unroll
    for (int reg = 0; reg < 4; ++reg) {
        float e = ell[reg];
        e += __shfl_xor(e, 1);
        e += __shfl_xor(e, 2);
        e += __shfl_xor(e, 4);
        e += __shfl_xor(e, 8);
        ell[reg] = 1.0f / e;
    }

    // ---- scatter O rows by rank ----
#pragma unroll
    for (int reg = 0; reg < 4; ++reg) {
        float* orow = out + (((size_t)b * LL + rk[reg]) * HH + h) * DD;
#pragma unroll
        for (int nt = 0; nt < 4; ++nt)
            orow[nt * 16 + cl] = accO[nt][reg] * ell[reg];
    }
}

extern "C" void kernel_launch(void* const* d_in, const int* in_sizes, int n_in,
                              void* d_out, int out_size, void* d_ws, size_t ws_size,
                              hipStream_t stream) {
    const float* Q = (const float*)d_in[0];
    const float* K = (const float*)d_in[1];
    const float* V = (const float*)d_in[2];
    float* out = (float*)d_out;

    int*   rank = (int*)((char*)d_ws + 131072);          // 128 KB
    float* maxs = (float*)((char*)d_ws + 262144);        // 128 KB

    // stage-A partials live in the first 512 KB of d_out (overwritten later)
    msp_partial<<<BB * HH * (LL / 128) * 2, 256, 0, stream>>>(Q, K, out);
    sort_rank<<<BB * HH, 256, 0, stream>>>(out, maxs, rank);
    flash_mfma<<<BB * HH * (LL / 64), 256, 0, stream>>>(Q, K, V, maxs, rank, out);
}

// Round 7
// 476.325 us; speedup vs baseline: 1.5074x; 1.0006x over previous
//
#include <hip/hip_runtime.h>
#include <math.h>

#define BB 2
#define LL 2048
#define SS 2048
#define HH 8
#define EE 64
#define DD 64
#define HE (HH * EE)   // 512
// softmax scale = 1/sqrt(E) = 0.125

// ws layout (384 KB):
//   [0, 128K)     : (unused -- m32 slot kept for layout stability)
//   [128K, 256K)  : rank (B*H*L ints)
//   [256K, 384K)  : maxs (B*H*L floats)
// d_out doubles as scratch for stage-A partials (512 KB of its 8 MB):
//   pmax[hf][bh][l] at out[ (hf*16+bh)*2048 + l ]
//   psum[hf][bh][l] at out[ 65536 + (hf*16+bh)*2048 + l ]
// flash_mfma fully overwrites out afterwards.

typedef __attribute__((ext_vector_type(8))) short   bf16x8;   // MFMA A/B frag
typedef __attribute__((ext_vector_type(4))) float   f32x4;    // MFMA C/D frag
typedef __attribute__((ext_vector_type(8))) unsigned short u16x8;
typedef __attribute__((ext_vector_type(4))) unsigned short u16x4;

__device__ __forceinline__ unsigned short f2bf(float x) {   // fp32 -> bf16 RNE
    unsigned int u = __float_as_uint(x);
    return (unsigned short)((u + 0x7FFFu + ((u >> 16) & 1u)) >> 16);
}

// ---------- A: BLAS-grid fp32 M_sp partials, LDS dbuf, 2 q/lane, key-split
// Arithmetic sequence IDENTICAL to the verified kernel, applied per query:
// score = sequential fmaf chain e=0..63 asc, single accumulator;
// r[j] chain over i8=0..15 sequential within each 128-key blk (bg = key/128);
// sub_ww = ((blk[4ww]+blk[4ww+1])+(blk[4ww+2]+blk[4ww+3]));
// s2048 = ((sub0+sub1)+(sub2+sub3)).  DO NOT REORDER.
//
// Occupancy forensics (R1 vs R4/R6): 2-block/CU co-residency succeeded at
// LDS_Block_Size 34816 (R1, 22.5% occ) and failed at 38912 (R6, 11.7% occ,
// serial blocks) with VGPR in the same 2-waves/SIMD band -> usable LDS pool
// for co-residency is between 69.6 KB and 77.8 KB. Fix: alias the post-loop
// reduction arrays (6 KB) into the dead ldsK staging buffer -> block LDS
// 38912 -> 32768; 2 blocks = 64 KB, inside the proven envelope.
// launch_bounds(256,1): VGPR cap 256, measured 172, no spill (R5 lesson:
// >=512-thread blocks force a 128 cap and spill qf).
__global__ __launch_bounds__(256, 1)
void msp_partial(const float* __restrict__ Q, const float* __restrict__ K,
                 float* __restrict__ pscratch) {
#pragma clang fp contract(off)
    // single 32 KB arena: main loop = ldsK[4][2][1024]; after a barrier the
    // first 1536 floats are reused as smx[2][4][64] + sblk[2][8][64].
    __shared__ __align__(16) float ldsAll[4 * 2 * 1024];   // 32768 B

    const int bid = blockIdx.x;          // 512 = hf*256 + bh*16 + lt
    const int hf = bid >> 8;             // key half 0/1
    const int rem = bid & 255;
    const int lt = rem & 15, bh = rem >> 4;
    const int h = bh & 7, b = bh >> 3;
    const int t = threadIdx.x, lq = t & 63, w = t >> 6;   // w = 0..3
    const int l0 = lt * 128 + lq;        // first query of this lane
    const int l1 = l0 + 64;              // second query of this lane

    float qf0[64], qf1[64];
    {
        const float4* q0 = (const float4*)(Q + (((size_t)b * LL + l0) * HH + h) * EE);
        const float4* q1 = (const float4*)(Q + (((size_t)b * LL + l1) * HH + h) * EE);
#pragma unroll
        for (int i = 0; i < 16; i++) {
            float4 v = q0[i];
            qf0[4*i] = v.x; qf0[4*i+1] = v.y; qf0[4*i+2] = v.z; qf0[4*i+3] = v.w;
        }
#pragma unroll
        for (int i = 0; i < 16; i++) {
            float4 v = q1[i];
            qf1[4*i] = v.x; qf1[4*i+1] = v.y; qf1[4*i+2] = v.z; qf1[4*i+3] = v.w;
        }
    }

    const int wu = __builtin_amdgcn_readfirstlane(w);
    const float* Kb = K + (((size_t)b * SS) * HH + h) * EE;

    // staging map: lane covers key row (lq>>2) of the 16-key chunk,
    // 4x float4 at float col (lq&3)*4 + {0,16,32,48}.
    // Wave key base = hf*1024 + wu*256.
    const float* gstage =
        Kb + (size_t)(hf * 1024 + wu * 256 + (lq >> 2)) * HE + (lq & 3) * 4;
    const int lslot = (lq >> 2) * 64 + (lq & 3) * 4;

    float4 pf0, pf1, pf2, pf3;
    {   // prologue: chunk 0 -> buf 0
        const float* s = gstage;
        pf0 = *(const float4*)(s);
        pf1 = *(const float4*)(s + 16);
        pf2 = *(const float4*)(s + 32);
        pf3 = *(const float4*)(s + 48);
        float* dst = &ldsAll[(wu * 2 + 0) * 1024 + lslot];
        *(float4*)(dst)      = pf0;
        *(float4*)(dst + 16) = pf1;
        *(float4*)(dst + 32) = pf2;
        *(float4*)(dst + 48) = pf3;
    }

    float mx0 = -1e30f, mx1 = -1e30f;
    float blk0[2], blk1[2];
#pragma unroll 1
    for (int lb = 0; lb < 2; ++lb) {     // local 128-key blk; global = 8hf+2w+lb
        float r0[8], r1[8];
#pragma unroll 1
        for (int ch = 0; ch < 8; ++ch) {
            const int g = lb * 8 + ch;                 // chunk 0..15
            const int gn = (g < 15) ? (g + 1) : 15;    // tail: reload (discarded)

            // issue next-chunk global loads (land after compute, before write)
            const float* s = gstage + (size_t)gn * (16 * HE);
            pf0 = *(const float4*)(s);
            pf1 = *(const float4*)(s + 16);
            pf2 = *(const float4*)(s + 32);
            pf3 = *(const float4*)(s + 48);

            const float* kb = &ldsAll[(wu * 2 + (g & 1)) * 1024];
#pragma unroll 1
            for (int i2 = 0; i2 < 2; ++i2) {
                const int i8 = ch * 2 + i2;            // 0..15 within the blk
                float c[8], d[8];
#pragma unroll
                for (int j = 0; j < 8; j++) { c[j] = 0.f; d[j] = 0.f; }
#pragma unroll
                for (int e4 = 0; e4 < 16; ++e4) {
#pragma unroll
                    for (int j = 0; j < 8; j++) {
                        const float4 kv =
                            *(const float4*)&kb[(i2 * 8 + j) * 64 + e4 * 4];
                        c[j] = fmaf(qf0[4*e4+0], kv.x, c[j]);
                        c[j] = fmaf(qf0[4*e4+1], kv.y, c[j]);
                        c[j] = fmaf(qf0[4*e4+2], kv.z, c[j]);
                        c[j] = fmaf(qf0[4*e4+3], kv.w, c[j]);
                        d[j] = fmaf(qf1[4*e4+0], kv.x, d[j]);
                        d[j] = fmaf(qf1[4*e4+1], kv.y, d[j]);
                        d[j] = fmaf(qf1[4*e4+2], kv.z, d[j]);
                        d[j] = fmaf(qf1[4*e4+3], kv.w, d[j]);
                    }
                }
#pragma unroll
                for (int j = 0; j < 8; j++) {
                    mx0 = fmaxf(mx0, c[j]);
                    mx1 = fmaxf(mx1, d[j]);
                    if (i8 == 0) { r0[j] = c[j];               r1[j] = d[j]; }
                    else         { r0[j] = __fadd_rn(r0[j], c[j]);
                                   r1[j] = __fadd_rn(r1[j], d[j]); }
                }
            }

            // write prefetched chunk g+1 into the other wave-private buffer
            float* dst = &ldsAll[(wu * 2 + ((g + 1) & 1)) * 1024 + lslot];
            *(float4*)(dst)      = pf0;
            *(float4*)(dst + 16) = pf1;
            *(float4*)(dst + 32) = pf2;
            *(float4*)(dst + 48) = pf3;
        }
        blk0[lb] = __fadd_rn(
            __fadd_rn(__fadd_rn(r0[0], r0[1]), __fadd_rn(r0[2], r0[3])),
            __fadd_rn(__fadd_rn(r0[4], r0[5]), __fadd_rn(r0[6], r0[7])));
        blk1[lb] = __fadd_rn(
            __fadd_rn(__fadd_rn(r1[0], r1[1]), __fadd_rn(r1[2], r1[3])),
            __fadd_rn(__fadd_rn(r1[4], r1[5]), __fadd_rn(r1[6], r1[7])));
    }

    // ---- reduction arrays alias the (now dead) staging arena ----
    __syncthreads();                      // all waves done with ldsK
    float* smx  = ldsAll;                 // [2][4][64]: (half*4 + w)*64 + lq
    float* sblk = ldsAll + 512;           // [2][8][64]: (half*8 + blk)*64 + lq
    smx[(0 * 4 + w) * 64 + lq] = mx0;
    smx[(1 * 4 + w) * 64 + lq] = mx1;
    sblk[(0 * 8 + 2 * w + 0) * 64 + lq] = blk0[0];  // local blk 0..7 = global 8hf..8hf+7
    sblk[(0 * 8 + 2 * w + 1) * 64 + lq] = blk0[1];
    sblk[(1 * 8 + 2 * w + 0) * 64 + lq] = blk1[0];
    sblk[(1 * 8 + 2 * w + 1) * 64 + lq] = blk1[1];
    __syncthreads();
    if (w < 2) {     // wave 0 finalizes query half 0, wave 1 half 1
        const int half = w;
        float m_all = fmaxf(fmaxf(smx[(half * 4 + 0) * 64 + lq],
                                  smx[(half * 4 + 1) * 64 + lq]),
                            fmaxf(smx[(half * 4 + 2) * 64 + lq],
                                  smx[(half * 4 + 3) * 64 + lq]));
        // sub_{2hf}   = tree over local blks 0..3  (= global 8hf..8hf+3)
        // sub_{2hf+1} = tree over local blks 4..7  (= global 8hf+4..8hf+7)
        const float sub_lo = __fadd_rn(
            __fadd_rn(sblk[(half * 8 + 0) * 64 + lq], sblk[(half * 8 + 1) * 64 + lq]),
            __fadd_rn(sblk[(half * 8 + 2) * 64 + lq], sblk[(half * 8 + 3) * 64 + lq]));
        const float sub_hi = __fadd_rn(
            __fadd_rn(sblk[(half * 8 + 4) * 64 + lq], sblk[(half * 8 + 5) * 64 + lq]),
            __fadd_rn(sblk[(half * 8 + 6) * 64 + lq], sblk[(half * 8 + 7) * 64 + lq]));
        const float psum = __fadd_rn(sub_lo, sub_hi);
        const int l = lt * 128 + half * 64 + lq;
        pscratch[(((size_t)hf * 16 + bh) << 11) + l]         = m_all;   // pmax
        pscratch[65536 + (((size_t)hf * 16 + bh) << 11) + l] = psum;    // psum
    }
}

// ---------- B: combine partials + descending sort, ties -> lower index ----
__global__ __launch_bounds__(256)
void sort_rank(const float* __restrict__ pscratch, float* __restrict__ maxs,
               int* __restrict__ rank) {
    __shared__ unsigned int k1[2048];
    __shared__ int pay[2048];
    const int bh = blockIdx.x;
    const int t = threadIdx.x;
    for (int i = t; i < 2048; i += 256) {
        // finish the exact verified combine tree:
        // m_all = fmax(pmax0, pmax1); s2048 = fadd(psum0, psum1)
        const float pmax0 = pscratch[(((size_t)bh) << 11) + i];
        const float pmax1 = pscratch[(((size_t)16 + bh) << 11) + i];
        const float psum0 = pscratch[65536 + (((size_t)bh) << 11) + i];
        const float psum1 = pscratch[65536 + (((size_t)16 + bh) << 11) + i];
        const float m_all = fmaxf(pmax0, pmax1);
        const float s2048 = __fadd_rn(psum0, psum1);
        const float mean  = __fmul_rn(s2048, 0.00048828125f);  // /2048 exact
        const float msp   = __fsub_rn(m_all, mean);
        maxs[(((size_t)bh) << 11) + i] = m_all;
        unsigned int u = __float_as_uint(msp);
        u = (u & 0x80000000u) ? ~u : (u | 0x80000000u);
        k1[i] = u; pay[i] = i;
    }
    __syncthreads();
    for (int k = 2; k <= 2048; k <<= 1) {
        for (int j = k >> 1; j > 0; j >>= 1) {
            for (int i = t; i < 2048; i += 256) {
                const int ixj = i ^ j;
                if (ixj > i) {
                    unsigned int a1 = k1[i], c1 = k1[ixj];
                    int pa = pay[i], pc = pay[ixj];
                    const bool pre = (a1 > c1) || (a1 == c1 && pa < pc);
                    const bool dir = ((i & k) == 0);
                    if (dir != pre) {
                        k1[i] = c1; k1[ixj] = a1;
                        pay[i] = pc; pay[ixj] = pa;
                    }
                }
            }
            __syncthreads();
        }
    }
    for (int i = t; i < 2048; i += 256)
        rank[(((size_t)bh) << 11) + pay[i]] = i;   // inverse permutation
}

// ---------- C: bf16 MFMA flash (two-pass softmax), scatter by rank --------
// Wave w owns 16 queries (rows lt*64 + w*16 .. +15) over the FULL S range.
// Per 64-s chunk: QK via mfma_16x16x32_bf16 (8), exp, P->LDS (A-layout),
// PV via mfma (8). K staged [s][e], V staged transposed [d][s], pitch 72
// bf16 (16B-aligned rows, bank-spread).
__global__ __launch_bounds__(256, 2)
void flash_mfma(const float* __restrict__ Q, const float* __restrict__ K,
                const float* __restrict__ V, const float* __restrict__ maxs,
                const int* __restrict__ rank, float* __restrict__ out) {
    __shared__ unsigned short ldsK[64 * 72];        // 9216 B
    __shared__ unsigned short ldsVT[64 * 72];       // 9216 B  (V transposed)
    __shared__ unsigned short ldsP[4 * 16 * 72];    // 9216 B  (per-wave P)

    const int bid = blockIdx.x;          // 512
    const int lt = bid & 31, bh = bid >> 5;
    const int h = bh & 7, b = bh >> 3;
    const int t = threadIdx.x, lane = t & 63, w = t >> 6;
    const int quad = lane >> 4, cl = lane & 15;

    const size_t kvbase = (((size_t)b * SS) * HH + h) * EE;

    // Q A-frags: A[m=cl][k=quad*8+j (+32*ef)]
    bf16x8 qa[2];
    {
        const float* qp = Q + (((size_t)b * LL + (lt * 64 + w * 16 + cl)) * HH + h) * EE
                          + quad * 8;
#pragma unroll
        for (int ef = 0; ef < 2; ++ef) {
            float4 a0 = *(const float4*)(qp + ef * 32);
            float4 a1 = *(const float4*)(qp + ef * 32 + 4);
            short* s = (short*)&qa[ef];
            s[0] = (short)f2bf(a0.x); s[1] = (short)f2bf(a0.y);
            s[2] = (short)f2bf(a0.z); s[3] = (short)f2bf(a0.w);
            s[4] = (short)f2bf(a1.x); s[5] = (short)f2bf(a1.y);
            s[6] = (short)f2bf(a1.z); s[7] = (short)f2bf(a1.w);
        }
    }

    // per-lane row constants (rows quad*4+reg)
    float negpm[4];
    int rk[4];
#pragma unroll
    for (int reg = 0; reg < 4; ++reg) {
        const int qg = lt * 64 + w * 16 + quad * 4 + reg;
        negpm[reg] = -0.125f * maxs[((size_t)bh << 11) + qg];
        rk[reg]    = rank[((size_t)bh << 11) + qg];
    }

    f32x4 accO[4];
#pragma unroll
    for (int nt = 0; nt < 4; ++nt) accO[nt] = (f32x4){0.f, 0.f, 0.f, 0.f};
    float ell[4] = {0.f, 0.f, 0.f, 0.f};

    const int pbase = w * (16 * 72);

#pragma unroll 1
    for (int c0 = 0; c0 < SS; c0 += 64) {
        __syncthreads();
        // ---- stage K[s][e] -> bf16, row-major pitch 72 ----
        {
            const int row = t >> 2, col0 = (t & 3) * 16;
            const float* gp = K + kvbase + (size_t)(c0 + row) * HE + col0;
            float4 f0 = ((const float4*)gp)[0];
            float4 f1 = ((const float4*)gp)[1];
            float4 f2 = ((const float4*)gp)[2];
            float4 f3 = ((const float4*)gp)[3];
            u16x8 w0 = { f2bf(f0.x), f2bf(f0.y), f2bf(f0.z), f2bf(f0.w),
                         f2bf(f1.x), f2bf(f1.y), f2bf(f1.z), f2bf(f1.w) };
            u16x8 w1 = { f2bf(f2.x), f2bf(f2.y), f2bf(f2.z), f2bf(f2.w),
                         f2bf(f3.x), f2bf(f3.y), f2bf(f3.z), f2bf(f3.w) };
            *(u16x8*)&ldsK[row * 72 + col0]     = w0;
            *(u16x8*)&ldsK[row * 72 + col0 + 8] = w1;
        }
        // ---- stage V transposed: VT[d][s] bf16, pitch 72 ----
        {
            const int s0 = (t & 15) * 4, d0 = (t >> 4) * 4;
            const float* gv = V + kvbase + (size_t)(c0 + s0) * HE + d0;
            float4 v0 = *(const float4*)(gv);
            float4 v1 = *(const float4*)(gv + HE);
            float4 v2 = *(const float4*)(gv + 2 * HE);
            float4 v3 = *(const float4*)(gv + 3 * HE);
            u16x4 p0 = { f2bf(v0.x), f2bf(v1.x), f2bf(v2.x), f2bf(v3.x) };
            u16x4 p1 = { f2bf(v0.y), f2bf(v1.y), f2bf(v2.y), f2bf(v3.y) };
            u16x4 p2 = { f2bf(v0.z), f2bf(v1.z), f2bf(v2.z), f2bf(v3.z) };
            u16x4 p3 = { f2bf(v0.w), f2bf(v1.w), f2bf(v2.w), f2bf(v3.w) };
            *(u16x4*)&ldsVT[(d0 + 0) * 72 + s0] = p0;
            *(u16x4*)&ldsVT[(d0 + 1) * 72 + s0] = p1;
            *(u16x4*)&ldsVT[(d0 + 2) * 72 + s0] = p2;
            *(u16x4*)&ldsVT[(d0 + 3) * 72 + s0] = p3;
        }
        __syncthreads();

        // ---- QK^T: S[m=q16][n=s64] = A(Q) x B(K), B[k=e][n=s]=K[s][e] ----
        f32x4 Sc[4];
#pragma unroll
        for (int nt = 0; nt < 4; ++nt) {
            bf16x8 bk0 = *(const bf16x8*)&ldsK[(nt * 16 + cl) * 72 + quad * 8];
            bf16x8 bk1 = *(const bf16x8*)&ldsK[(nt * 16 + cl) * 72 + quad * 8 + 32];
            f32x4 z = (f32x4){0.f, 0.f, 0.f, 0.f};
            z = __builtin_amdgcn_mfma_f32_16x16x32_bf16(qa[0], bk0, z, 0, 0, 0);
            z = __builtin_amdgcn_mfma_f32_16x16x32_bf16(qa[1], bk1, z, 0, 0, 0);
            Sc[nt] = z;
        }

        // ---- softmax numerator + P (bf16) into A-layout LDS ----
#pragma unroll
        for (int nt = 0; nt < 4; ++nt) {
#pragma unroll
            for (int reg = 0; reg < 4; ++reg) {
                const float p = __expf(fmaf(Sc[nt][reg], 0.125f, negpm[reg]));
                ell[reg] += p;
                ldsP[pbase + (quad * 4 + reg) * 72 + nt * 16 + cl] = f2bf(p);
            }
        }

        // ---- PV: O[m=q16][n=d64] += A(P) x B(V), B[k=s][n=d]=VT[d][s] ----
        bf16x8 pa0 = *(const bf16x8*)&ldsP[pbase + cl * 72 + quad * 8];
        bf16x8 pa1 = *(const bf16x8*)&ldsP[pbase + cl * 72 + quad * 8 + 32];
#pragma unroll
        for (int nt = 0; nt < 4; ++nt) {
            bf16x8 bv0 = *(const bf16x8*)&ldsVT[(nt * 16 + cl) * 72 + quad * 8];
            bf16x8 bv1 = *(const bf16x8*)&ldsVT[(nt * 16 + cl) * 72 + quad * 8 + 32];
            accO[nt] = __builtin_amdgcn_mfma_f32_16x16x32_bf16(pa0, bv0, accO[nt], 0, 0, 0);
            accO[nt] = __builtin_amdgcn_mfma_f32_16x16x32_bf16(pa1, bv1, accO[nt], 0, 0, 0);
        }
    }

    // ---- ell: reduce across the 16 lanes sharing each row (within quad) ----
#pragma unroll
    for (int reg = 0; reg < 4; ++reg) {
        float e = ell[reg];
        e += __shfl_xor(e, 1);
        e += __shfl_xor(e, 2);
        e += __shfl_xor(e, 4);
        e += __shfl_xor(e, 8);
        ell[reg] = 1.0f / e;
    }

    // ---- scatter O rows by rank ----
#pragma unroll
    for (int reg = 0; reg < 4; ++reg) {
        float* orow = out + (((size_t)b * LL + rk[reg]) * HH + h) * DD;
#pragma unroll
        for (int nt = 0; nt < 4; ++nt)
            orow[nt * 16 + cl] = accO[nt][reg] * ell[reg];
    }
}

extern "C" void kernel_launch(void* const* d_in, const int* in_sizes, int n_in,
                              void* d_out, int out_size, void* d_ws, size_t ws_size,
                              hipStream_t stream) {
    const float* Q = (const float*)d_in[0];
    const float* K = (const float*)d_in[1];
    const float* V = (const float*)d_in[2];
    float* out = (float*)d_out;

    int*   rank = (int*)((char*)d_ws + 131072);          // 128 KB
    float* maxs = (float*)((char*)d_ws + 262144);        // 128 KB

    // stage-A partials live in the first 512 KB of d_out (overwritten later)
    msp_partial<<<BB * HH * (LL / 128) * 2, 256, 0, stream>>>(Q, K, out);
    sort_rank<<<BB * HH, 256, 0, stream>>>(out, maxs, rank);
    flash_mfma<<<BB * HH * (LL / 64), 256, 0, stream>>>(Q, K, V, maxs, rank, out);
}

// Round 8
// 404.654 us; speedup vs baseline: 1.7744x; 1.1771x over previous
//
#include <hip/hip_runtime.h>
#include <math.h>

#define BB 2
#define LL 2048
#define SS 2048
#define HH 8
#define EE 64
#define DD 64
#define HE (HH * EE)   // 512
// softmax scale = 1/sqrt(E) = 0.125

// ws layout (384 KB):
//   [0, 128K)     : m32  (B*H*L floats) -- BLAS-grid fp32 M_sp (bit-exact)
//   [128K, 256K)  : rank (B*H*L ints)
//   [256K, 384K)  : maxs (B*H*L floats)

typedef __attribute__((ext_vector_type(8))) short   bf16x8;   // MFMA A/B frag
typedef __attribute__((ext_vector_type(4))) float   f32x4;    // MFMA C/D frag
typedef __attribute__((ext_vector_type(8))) unsigned short u16x8;
typedef __attribute__((ext_vector_type(4))) unsigned short u16x4;

__device__ __forceinline__ unsigned short f2bf(float x) {   // fp32 -> bf16 RNE
    unsigned int u = __float_as_uint(x);
    return (unsigned short)((u + 0x7FFFu + ((u >> 16) & 1u)) >> 16);
}

__device__ __forceinline__ float rdlane(float v, int lane) { // bit-exact copy
    return __uint_as_float(
        (unsigned)__builtin_amdgcn_readlane((int)__float_as_uint(v), lane));
}

// ---------- A: BLAS-grid fp32 M_sp, K via VMEM-load + v_readlane broadcast
// Arithmetic sequence IDENTICAL to the verified kernel:
// score = sequential fmaf chain e=0..63 asc, single accumulator (c[j] gets
// its updates in ascending-e order; j-interleaving does not touch any
// individual chain); r[j] chain over i8=0..15 sequential; blk[lf] =
// exact-halves tree over r[0..7]; sub = ((blk0+blk1)+(blk2+blk3));
// s2048 = ((sub0+sub1)+(sub2+sub3)).  DO NOT REORDER.
//
// Occupancy model (R1..R7 forensics): multi-wave residency requires
// VGPR <= 128 (effective ~256-VGPR/SIMD multi-wave budget: R1 116 -> 2
// waves/SIMD; R6/R7 172 -> 1 wave/SIMD regardless of LDS). Therefore
// 1 query/lane (qf = 64 VGPRs) and NO LDS broadcast (that path's wall is
// 327us, R1). Instead: 4 keys per global_load_dwordx4 (lane ln holds
// K[j0+(ln>>4)][4*(ln&15)..+3], coalesced 4x256B), then per element
// K[j][e] = readlane(comp e&3, lane (j&3)*16 + (e>>2)) -> SGPR -> scalar
// operand of fmaf. readlane is VALU-pipe, loads are vmcnt-pipelined
// in-order (no SMEM OOO drain, no LDS pipe). ~2x VALU floor = ~110us.
__global__ __launch_bounds__(256, 2)
void msp_blas(const float* __restrict__ Q, const float* __restrict__ K,
              float* __restrict__ m32, float* __restrict__ maxs) {
#pragma clang fp contract(off)
    const int bid = blockIdx.x;          // B*H*32 = 512
    const int lt = bid & 31, bh = bid >> 5;
    const int h = bh & 7, b = bh >> 3;
    const int t = threadIdx.x, lq = t & 63, w = t >> 6;
    const int l = lt * 64 + lq;

    float qf[64];
    const float4* qrow = (const float4*)(Q + (((size_t)b * LL + l) * HH + h) * EE);
#pragma unroll
    for (int i = 0; i < 16; i++) {
        float4 v = qrow[i];
        qf[4*i] = v.x; qf[4*i+1] = v.y; qf[4*i+2] = v.z; qf[4*i+3] = v.w;
    }

    // wave w owns keys [512w, 512w+512) (same as verified kernel)
    const float* Kw = K + (((size_t)b * SS) * HH + h) * EE + (size_t)w * 512 * HE;
    // per-lane load base: key j0+(lq>>4), floats 4*(lq&15)..+3
    const float* gld = Kw + (size_t)(lq >> 4) * HE + (lq & 15) * 4;

    // double-buffered 8-key groups: A = keys g..g+3, B = keys g+4..g+7
    float4 A0 = *(const float4*)(gld);
    float4 B0 = *(const float4*)(gld + 4 * HE);

    float mx = -1e30f;
    float blk[4];
#pragma unroll 1
    for (int lf = 0; lf < 4; ++lf) {
        float r[8];
#pragma unroll 1
        for (int i8 = 0; i8 < 16; ++i8) {
            const int kc = lf * 128 + i8 * 8;            // this group's base key
            const int kn = (kc < 504) ? kc + 8 : 504;    // next (tail: reload)

            // issue next-group loads; consumed only at the A0=A1 copy below,
            // so they stay in flight across the whole 1024-instr compute.
            float4 A1 = *(const float4*)(gld + (size_t)kn * HE);
            float4 B1 = *(const float4*)(gld + (size_t)(kn + 4) * HE);

            float c[8];
#pragma unroll
            for (int j = 0; j < 8; ++j) c[j] = 0.f;
            // keys j=0..3 from A0, j=4..7 from B0. Each c[j] is a strictly
            // e-ascending fmaf chain (bit-exact vs verified kernel).
#pragma unroll
            for (int j = 0; j < 4; ++j) {
#pragma unroll
                for (int e4 = 0; e4 < 16; ++e4) {
                    const int ln = j * 16 + e4;
                    c[j] = fmaf(qf[4*e4+0], rdlane(A0.x, ln), c[j]);
                    c[j] = fmaf(qf[4*e4+1], rdlane(A0.y, ln), c[j]);
                    c[j] = fmaf(qf[4*e4+2], rdlane(A0.z, ln), c[j]);
                    c[j] = fmaf(qf[4*e4+3], rdlane(A0.w, ln), c[j]);
                }
            }
#pragma unroll
            for (int j = 0; j < 4; ++j) {
#pragma unroll
                for (int e4 = 0; e4 < 16; ++e4) {
                    const int ln = j * 16 + e4;
                    c[4+j] = fmaf(qf[4*e4+0], rdlane(B0.x, ln), c[4+j]);
                    c[4+j] = fmaf(qf[4*e4+1], rdlane(B0.y, ln), c[4+j]);
                    c[4+j] = fmaf(qf[4*e4+2], rdlane(B0.z, ln), c[4+j]);
                    c[4+j] = fmaf(qf[4*e4+3], rdlane(B0.w, ln), c[4+j]);
                }
            }
#pragma unroll
            for (int j = 0; j < 8; ++j) {
                mx = fmaxf(mx, c[j]);
                if (i8 == 0) r[j] = c[j];
                else         r[j] = __fadd_rn(r[j], c[j]);
            }
            A0 = A1; B0 = B1;   // vmcnt wait lands here, after compute
        }
        blk[lf] = __fadd_rn(
            __fadd_rn(__fadd_rn(r[0], r[1]), __fadd_rn(r[2], r[3])),
            __fadd_rn(__fadd_rn(r[4], r[5]), __fadd_rn(r[6], r[7])));
    }
    const float sub = __fadd_rn(__fadd_rn(blk[0], blk[1]),
                                __fadd_rn(blk[2], blk[3]));

    __shared__ float smx[4][64], ssub[4][64];
    smx[w][lq] = mx; ssub[w][lq] = sub;
    __syncthreads();
    if (w == 0) {
        const float m_all = fmaxf(fmaxf(smx[0][lq], smx[1][lq]),
                                  fmaxf(smx[2][lq], smx[3][lq]));
        const float s2048 = __fadd_rn(__fadd_rn(ssub[0][lq], ssub[1][lq]),
                                      __fadd_rn(ssub[2][lq], ssub[3][lq]));
        const float mean = __fmul_rn(s2048, 0.00048828125f);  // /2048 exact
        m32[((size_t)bh << 11) + l]  = __fsub_rn(m_all, mean);
        maxs[((size_t)bh << 11) + l] = m_all;
    }
}

// ---------- B: descending sort, ties -> lower index first -----------------
__global__ __launch_bounds__(256)
void sort_rank(const float* __restrict__ m32, int* __restrict__ rank) {
    __shared__ unsigned int k1[2048];
    __shared__ int pay[2048];
    const int bh = blockIdx.x;
    const int t = threadIdx.x;
    for (int i = t; i < 2048; i += 256) {
        unsigned int u = __float_as_uint(m32[((size_t)bh << 11) + i]);
        u = (u & 0x80000000u) ? ~u : (u | 0x80000000u);
        k1[i] = u; pay[i] = i;
    }
    __syncthreads();
    for (int k = 2; k <= 2048; k <<= 1) {
        for (int j = k >> 1; j > 0; j >>= 1) {
            for (int i = t; i < 2048; i += 256) {
                const int ixj = i ^ j;
                if (ixj > i) {
                    unsigned int a1 = k1[i], c1 = k1[ixj];
                    int pa = pay[i], pc = pay[ixj];
                    const bool pre = (a1 > c1) || (a1 == c1 && pa < pc);
                    const bool dir = ((i & k) == 0);
                    if (dir != pre) {
                        k1[i] = c1; k1[ixj] = a1;
                        pay[i] = pc; pay[ixj] = pa;
                    }
                }
            }
            __syncthreads();
        }
    }
    for (int i = t; i < 2048; i += 256)
        rank[((size_t)bh << 11) + pay[i]] = i;   // inverse permutation
}

// ---------- C: bf16 MFMA flash (two-pass softmax), scatter by rank --------
// Wave w owns 16 queries (rows lt*64 + w*16 .. +15) over the FULL S range.
// Per 64-s chunk: QK via mfma_16x16x32_bf16 (8), exp, P->LDS (A-layout),
// PV via mfma (8). K staged [s][e], V staged transposed [d][s], pitch 72
// bf16 (16B-aligned rows, bank-spread).
__global__ __launch_bounds__(256, 2)
void flash_mfma(const float* __restrict__ Q, const float* __restrict__ K,
                const float* __restrict__ V, const float* __restrict__ maxs,
                const int* __restrict__ rank, float* __restrict__ out) {
    __shared__ unsigned short ldsK[64 * 72];        // 9216 B
    __shared__ unsigned short ldsVT[64 * 72];       // 9216 B  (V transposed)
    __shared__ unsigned short ldsP[4 * 16 * 72];    // 9216 B  (per-wave P)

    const int bid = blockIdx.x;          // 512
    const int lt = bid & 31, bh = bid >> 5;
    const int h = bh & 7, b = bh >> 3;
    const int t = threadIdx.x, lane = t & 63, w = t >> 6;
    const int quad = lane >> 4, cl = lane & 15;

    const size_t kvbase = (((size_t)b * SS) * HH + h) * EE;

    // Q A-frags: A[m=cl][k=quad*8+j (+32*ef)]
    bf16x8 qa[2];
    {
        const float* qp = Q + (((size_t)b * LL + (lt * 64 + w * 16 + cl)) * HH + h) * EE
                          + quad * 8;
#pragma unroll
        for (int ef = 0; ef < 2; ++ef) {
            float4 a0 = *(const float4*)(qp + ef * 32);
            float4 a1 = *(const float4*)(qp + ef * 32 + 4);
            short* s = (short*)&qa[ef];
            s[0] = (short)f2bf(a0.x); s[1] = (short)f2bf(a0.y);
            s[2] = (short)f2bf(a0.z); s[3] = (short)f2bf(a0.w);
            s[4] = (short)f2bf(a1.x); s[5] = (short)f2bf(a1.y);
            s[6] = (short)f2bf(a1.z); s[7] = (short)f2bf(a1.w);
        }
    }

    // per-lane row constants (rows quad*4+reg)
    float negpm[4];
    int rk[4];
#pragma unroll
    for (int reg = 0; reg < 4; ++reg) {
        const int qg = lt * 64 + w * 16 + quad * 4 + reg;
        negpm[reg] = -0.125f * maxs[((size_t)bh << 11) + qg];
        rk[reg]    = rank[((size_t)bh << 11) + qg];
    }

    f32x4 accO[4];
#pragma unroll
    for (int nt = 0; nt < 4; ++nt) accO[nt] = (f32x4){0.f, 0.f, 0.f, 0.f};
    float ell[4] = {0.f, 0.f, 0.f, 0.f};

    const int pbase = w * (16 * 72);

#pragma unroll 1
    for (int c0 = 0; c0 < SS; c0 += 64) {
        __syncthreads();
        // ---- stage K[s][e] -> bf16, row-major pitch 72 ----
        {
            const int row = t >> 2, col0 = (t & 3) * 16;
            const float* gp = K + kvbase + (size_t)(c0 + row) * HE + col0;
            float4 f0 = ((const float4*)gp)[0];
            float4 f1 = ((const float4*)gp)[1];
            float4 f2 = ((const float4*)gp)[2];
            float4 f3 = ((const float4*)gp)[3];
            u16x8 w0 = { f2bf(f0.x), f2bf(f0.y), f2bf(f0.z), f2bf(f0.w),
                         f2bf(f1.x), f2bf(f1.y), f2bf(f1.z), f2bf(f1.w) };
            u16x8 w1 = { f2bf(f2.x), f2bf(f2.y), f2bf(f2.z), f2bf(f2.w),
                         f2bf(f3.x), f2bf(f3.y), f2bf(f3.z), f2bf(f3.w) };
            *(u16x8*)&ldsK[row * 72 + col0]     = w0;
            *(u16x8*)&ldsK[row * 72 + col0 + 8] = w1;
        }
        // ---- stage V transposed: VT[d][s] bf16, pitch 72 ----
        {
            const int s0 = (t & 15) * 4, d0 = (t >> 4) * 4;
            const float* gv = V + kvbase + (size_t)(c0 + s0) * HE + d0;
            float4 v0 = *(const float4*)(gv);
            float4 v1 = *(const float4*)(gv + HE);
            float4 v2 = *(const float4*)(gv + 2 * HE);
            float4 v3 = *(const float4*)(gv + 3 * HE);
            u16x4 p0 = { f2bf(v0.x), f2bf(v1.x), f2bf(v2.x), f2bf(v3.x) };
            u16x4 p1 = { f2bf(v0.y), f2bf(v1.y), f2bf(v2.y), f2bf(v3.y) };
            u16x4 p2 = { f2bf(v0.z), f2bf(v1.z), f2bf(v2.z), f2bf(v3.z) };
            u16x4 p3 = { f2bf(v0.w), f2bf(v1.w), f2bf(v2.w), f2bf(v3.w) };
            *(u16x4*)&ldsVT[(d0 + 0) * 72 + s0] = p0;
            *(u16x4*)&ldsVT[(d0 + 1) * 72 + s0] = p1;
            *(u16x4*)&ldsVT[(d0 + 2) * 72 + s0] = p2;
            *(u16x4*)&ldsVT[(d0 + 3) * 72 + s0] = p3;
        }
        __syncthreads();

        // ---- QK^T: S[m=q16][n=s64] = A(Q) x B(K), B[k=e][n=s]=K[s][e] ----
        f32x4 Sc[4];
#pragma unroll
        for (int nt = 0; nt < 4; ++nt) {
            bf16x8 bk0 = *(const bf16x8*)&ldsK[(nt * 16 + cl) * 72 + quad * 8];
            bf16x8 bk1 = *(const bf16x8*)&ldsK[(nt * 16 + cl) * 72 + quad * 8 + 32];
            f32x4 z = (f32x4){0.f, 0.f, 0.f, 0.f};
            z = __builtin_amdgcn_mfma_f32_16x16x32_bf16(qa[0], bk0, z, 0, 0, 0);
            z = __builtin_amdgcn_mfma_f32_16x16x32_bf16(qa[1], bk1, z, 0, 0, 0);
            Sc[nt] = z;
        }

        // ---- softmax numerator + P (bf16) into A-layout LDS ----
#pragma unroll
        for (int nt = 0; nt < 4; ++nt) {
#pragma unroll
            for (int reg = 0; reg < 4; ++reg) {
                const float p = __expf(fmaf(Sc[nt][reg], 0.125f, negpm[reg]));
                ell[reg] += p;
                ldsP[pbase + (quad * 4 + reg) * 72 + nt * 16 + cl] = f2bf(p);
            }
        }

        // ---- PV: O[m=q16][n=d64] += A(P) x B(V), B[k=s][n=d]=VT[d][s] ----
        bf16x8 pa0 = *(const bf16x8*)&ldsP[pbase + cl * 72 + quad * 8];
        bf16x8 pa1 = *(const bf16x8*)&ldsP[pbase + cl * 72 + quad * 8 + 32];
#pragma unroll
        for (int nt = 0; nt < 4; ++nt) {
            bf16x8 bv0 = *(const bf16x8*)&ldsVT[(nt * 16 + cl) * 72 + quad * 8];
            bf16x8 bv1 = *(const bf16x8*)&ldsVT[(nt * 16 + cl) * 72 + quad * 8 + 32];
            accO[nt] = __builtin_amdgcn_mfma_f32_16x16x32_bf16(pa0, bv0, accO[nt], 0, 0, 0);
            accO[nt] = __builtin_amdgcn_mfma_f32_16x16x32_bf16(pa1, bv1, accO[nt], 0, 0, 0);
        }
    }

    // ---- ell: reduce across the 16 lanes sharing each row (within quad) ----
#pragma unroll
    for (int reg = 0; reg < 4; ++reg) {
        float e = ell[reg];
        e += __shfl_xor(e, 1);
        e += __shfl_xor(e, 2);
        e += __shfl_xor(e, 4);
        e += __shfl_xor(e, 8);
        ell[reg] = 1.0f / e;
    }

    // ---- scatter O rows by rank ----
#pragma unroll
    for (int reg = 0; reg < 4; ++reg) {
        float* orow = out + (((size_t)b * LL + rk[reg]) * HH + h) * DD;
#pragma unroll
        for (int nt = 0; nt < 4; ++nt)
            orow[nt * 16 + cl] = accO[nt][reg] * ell[reg];
    }
}

extern "C" void kernel_launch(void* const* d_in, const int* in_sizes, int n_in,
                              void* d_out, int out_size, void* d_ws, size_t ws_size,
                              hipStream_t stream) {
    const float* Q = (const float*)d_in[0];
    const float* K = (const float*)d_in[1];
    const float* V = (const float*)d_in[2];
    float* out = (float*)d_out;

    float* m32  = (float*)d_ws;                          // 128 KB
    int*   rank = (int*)((char*)d_ws + 131072);          // 128 KB
    float* maxs = (float*)((char*)d_ws + 262144);        // 128 KB

    msp_blas<<<BB * HH * (LL / 64), 256, 0, stream>>>(Q, K, m32, maxs);
    sort_rank<<<BB * HH, 256, 0, stream>>>(m32, rank);
    flash_mfma<<<BB * HH * (LL / 64), 256, 0, stream>>>(Q, K, V, maxs, rank, out);
}